// Round 6
// baseline (229.355 us; speedup 1.0000x reference)
//
#include <hip/hip_runtime.h>
#include <hip/hip_bf16.h>

#define NCAT 72
#define NCATP 80          // padded to 5 MFMA cat-tiles of 16
#define DIM 32
#define BNUM 4
#define TEMP_INV (1.0f / 0.07f)
#define SEG_W 10.0f

// ws layout (floats):
#define WS_SUMS 0         // [4][72][32]
#define WS_CNTS 9216      // [4][72]
#define WS_PROT 9504      // [4][80][32]  normalized prototypes, PADDED, absent/missing rows ZERO
#define WS_NABS 19744     // [4]          count of zero rows (exp2 contributes exactly 1 each)
#define WS_LOSS 19748     // [4]
#define WS_KEEP 19752     // [4]
#define WS_TOTAL 19756

typedef __attribute__((ext_vector_type(8))) short short8v;   // 8 bf16
typedef __attribute__((ext_vector_type(4))) float f32x4;

__device__ __forceinline__ bool is_missing(int c) {
    return (c == 13) | (c == 53) | (c == 61);
}

// float -> bf16(RNE) bits, and the fp32 value of that bf16 (for lo-split)
__device__ __forceinline__ short f2bf_hi(float f, float* hi_f) {
    unsigned u = __float_as_uint(f);
    unsigned r = u + 0x7FFFu + ((u >> 16) & 1u);
    *hi_f = __uint_as_float(r & 0xFFFF0000u);
    return (short)(r >> 16);
}
__device__ __forceinline__ short f2bf(float f) {
    unsigned u = __float_as_uint(f);
    unsigned r = u + 0x7FFFu + ((u >> 16) & 1u);
    return (short)(r >> 16);
}

// k_accum v3 (onehot-MFMA segment sum).
// R5 diagnosis: v2's commit was an 8-step sched_barrier-pinned LDS RMW chain
// (~1000 cyc / 32 points) holding k_accum ~2.3x above its 21us HBM floor.
// v3: sums[c][d] = onehot[c][p] . e_norm[p][d] on the matrix pipe.
//  - A = exact {0,1.0} bf16 onehot (validity folded in -> invalid rows = 0)
//  - B = normalized embedding, hi/lo bf16 split (exact to ~2^-17)
//  - counts = onehot . ones (exact integers in fp32 accum)
//  - accumulate in AGPRs across the whole loop; NO LDS in the hot loop.
// Flush once: per-wave C frags -> LDS [4][80][32] -> cross-wave reduce ->
// global atomics (1 per element per block).
template <int BPB>
__global__ __launch_bounds__(256, 3) void k_accum(const float* __restrict__ emb,
                                                  const int* __restrict__ lab,
                                                  float* __restrict__ ws, int Nb) {
    __shared__ float s_s[4][NCATP][DIM];   // 40.96 KB (fully written at flush)
    __shared__ float s_c[4][NCATP];        // 1.28 KB
    const int t = threadIdx.x;
    const int b = blockIdx.x / BPB;
    const int blk = blockIdx.x % BPB;
    const int w = t >> 6;
    const int lane = t & 63;
    const int lid = lane & 15;    // A: cat-in-tile | B: dim-in-tile | C: dim col
    const int kc = lane >> 4;     // k-chunk (8 points) | C: cat row-quad

    const float* eb = emb + (size_t)b * Nb * DIM;
    const int* lb = lab + (size_t)b * Nb;

    f32x4 accs[5][2];
    f32x4 accc[5];
    #pragma unroll
    for (int n = 0; n < 5; n++) {
        accs[n][0] = (f32x4){0.f, 0.f, 0.f, 0.f};
        accs[n][1] = (f32x4){0.f, 0.f, 0.f, 0.f};
        accc[n] = (f32x4){0.f, 0.f, 0.f, 0.f};
    }
    short8v bone;
    #pragma unroll
    for (int j = 0; j < 8; j++) bone[j] = (short)0x3F80;  // bf16 1.0

    #pragma unroll 1
    for (int p0 = blk * 32; p0 < Nb; p0 += BPB * 32) {
        const int pb = p0 + kc * 8;
        int lcl[8];
        int hi4[8];
        bool va[8];
        #pragma unroll
        for (int j = 0; j < 8; j++) {
            const int l = lb[pb + j];
            va[j] = (l >= 0);
            lcl[j] = min(max(l, 0), NCAT - 1);
            hi4[j] = lcl[j] >> 4;
        }
        float v0[8], v1[8];
        #pragma unroll
        for (int j = 0; j < 8; j++) {
            const float* r = eb + (size_t)(pb + j) * DIM;
            v0[j] = r[lid];
            v1[j] = r[lid + 16];
        }
        // per-point squared norm: reduce over the 16 lid-lanes
        float ssp[8];
        #pragma unroll
        for (int j = 0; j < 8; j++) ssp[j] = v0[j] * v0[j] + v1[j] * v1[j];
        #pragma unroll
        for (int m = 1; m <= 8; m <<= 1) {
            #pragma unroll
            for (int j = 0; j < 8; j++) ssp[j] += __shfl_xor(ssp[j], m);
        }
        // scale + bf16 hi/lo split -> B fragments
        short8v b0h, b0l, b1h, b1l;
        #pragma unroll
        for (int j = 0; j < 8; j++) {
            const float inv = 1.0f / fmaxf(sqrtf(ssp[j]), 1e-12f);
            float h;
            const float x0 = v0[j] * inv;
            b0h[j] = f2bf_hi(x0, &h); b0l[j] = f2bf(x0 - h);
            const float x1 = v1[j] * inv;
            b1h[j] = f2bf_hi(x1, &h); b1l[j] = f2bf(x1 - h);
        }
        // per-point "matches my lid" predicate (tile-independent part)
        short hit[8];
        #pragma unroll
        for (int j = 0; j < 8; j++)
            hit[j] = (va[j] && ((lcl[j] & 15) == lid)) ? (short)0x3F80 : (short)0;

        #pragma unroll
        for (int n = 0; n < 5; n++) {
            short8v a;
            #pragma unroll
            for (int j = 0; j < 8; j++) a[j] = (hi4[j] == n) ? hit[j] : (short)0;
            accs[n][0] = __builtin_amdgcn_mfma_f32_16x16x32_bf16(a, b0h, accs[n][0], 0, 0, 0);
            accs[n][0] = __builtin_amdgcn_mfma_f32_16x16x32_bf16(a, b0l, accs[n][0], 0, 0, 0);
            accs[n][1] = __builtin_amdgcn_mfma_f32_16x16x32_bf16(a, b1h, accs[n][1], 0, 0, 0);
            accs[n][1] = __builtin_amdgcn_mfma_f32_16x16x32_bf16(a, b1l, accs[n][1], 0, 0, 0);
            accc[n]    = __builtin_amdgcn_mfma_f32_16x16x32_bf16(a, bone, accc[n], 0, 0, 0);
        }
    }

    // ---- flush: C layout col=lid(dim), row=kc*4+r (cat-in-tile) ----
    #pragma unroll
    for (int n = 0; n < 5; n++) {
        const int cat = n * 16 + kc * 4;
        #pragma unroll
        for (int r = 0; r < 4; r++) {
            s_s[w][cat + r][lid] = accs[n][0][r];
            s_s[w][cat + r][lid + 16] = accs[n][1][r];
        }
        if (lid == 0) {
            #pragma unroll
            for (int r = 0; r < 4; r++) s_c[w][cat + r] = accc[n][r];
        }
    }
    __syncthreads();

    float* gs = ws + WS_SUMS + b * NCAT * DIM;
    for (int i = t; i < NCAT * DIM; i += 256) {
        const int c = i >> 5, d = i & 31;
        float val = s_s[0][c][d] + s_s[1][c][d] + s_s[2][c][d] + s_s[3][c][d];
        if (val != 0.f) unsafeAtomicAdd(&gs[i], val);
    }
    if (t < NCAT) {
        float cc = s_c[0][t] + s_c[1][t] + s_c[2][t] + s_c[3][t];
        if (cc != 0.f) unsafeAtomicAdd(ws + WS_CNTS + b * NCAT + t, cc);
    }
}

// One block per batch: normalize sums -> prototypes (padded, absent rows ZERO)
// and store n_absent = count of zero rows (incl. 8 pad rows).
__global__ __launch_bounds__(256) void k_proto(float* __restrict__ ws) {
    const int b = blockIdx.x;
    __shared__ float s_np;
    if (threadIdx.x == 0) s_np = 0.f;
    __syncthreads();
    const float* gs = ws + WS_SUMS + b * NCAT * DIM;
    const float* gc = ws + WS_CNTS + b * NCAT;
    float* gp = ws + WS_PROT + b * NCATP * DIM;
    const int dd = threadIdx.x & 31;
    const int r0 = threadIdx.x >> 5;
    for (int c = r0; c < NCAT; c += 8) {
        float cnt = gc[c];
        float val = gs[c * DIM + dd] / fmaxf(cnt, 1.0f);
        float ss = val * val;
        #pragma unroll
        for (int m = 16; m >= 1; m >>= 1) ss += __shfl_xor(ss, m);
        float inv = 1.0f / fmaxf(sqrtf(ss), 1e-12f);
        const bool present = (cnt > 0.f) && !is_missing(c);
        gp[c * DIM + dd] = present ? val * inv : 0.f;  // zero row -> exp2 term exactly 1
        if (dd == 0) unsafeAtomicAdd(&s_np, present ? 1.f : 0.f);
        // rows 72..79 remain zero from the memset
    }
    __syncthreads();
    if (threadIdx.x == 0) ws[WS_NABS + b] = (float)NCATP - s_np;
}

// One 16-point group: load, normalize, label-dot (exact fp32), bf16x3 MFMA
// against the wave-resident prototype fragments, softmax-sum, accumulate.
__device__ __forceinline__ void point_group(
    int pt, const float* __restrict__ eb, const int* __restrict__ lb,
    const float* __restrict__ pp, const short8v phi[5], const short8v plo[5],
    float nabs, int sub, float& lacc, float& kacc)
{
    const float LOG2E = 1.4426950408889634f;
    const int l = lb[pt];
    const int lc = min(max(l, 0), NCAT - 1);

    const float4* ep = (const float4*)(eb + (size_t)pt * DIM + sub * 8);
    float4 a0 = ep[0], a1 = ep[1];

    float ss = a0.x * a0.x + a0.y * a0.y + a0.z * a0.z + a0.w * a0.w +
               a1.x * a1.x + a1.y * a1.y + a1.z * a1.z + a1.w * a1.w;
    ss += __shfl_xor(ss, 16);
    ss += __shfl_xor(ss, 32);
    const float sca = (TEMP_INV * LOG2E) / fmaxf(sqrtf(ss), 1e-12f);
    a0.x *= sca; a0.y *= sca; a0.z *= sca; a0.w *= sca;
    a1.x *= sca; a1.y *= sca; a1.z *= sca; a1.w *= sca;

    // label logit (log2 units), exact fp32
    const float4* qk = (const float4*)(pp + lc * DIM + sub * 8);
    float4 q0 = qk[0], q1 = qk[1];
    float dl = q0.x * a0.x + q0.y * a0.y + q0.z * a0.z + q0.w * a0.w +
               q1.x * a1.x + q1.y * a1.y + q1.z * a1.z + q1.w * a1.w;
    dl += __shfl_xor(dl, 16);
    dl += __shfl_xor(dl, 32);

    const bool keep = (l >= 0) && !is_missing(lc);

    // bf16 hi/lo split of the scaled point (B fragment: col=lane&15=point)
    float ea[8] = {a0.x, a0.y, a0.z, a0.w, a1.x, a1.y, a1.z, a1.w};
    short8v ehi, elo;
    #pragma unroll
    for (int j = 0; j < 8; j++) {
        float hf;
        ehi[j] = f2bf_hi(ea[j], &hf);
        elo[j] = f2bf(ea[j] - hf);
    }

    // 5 cat-tiles: C col=point(lane&15), row=cat-in-tile=(sub*4+reg)
    float s = 0.f;
    #pragma unroll
    for (int n = 0; n < 5; n++) {
        f32x4 acc = {0.f, 0.f, 0.f, 0.f};
        acc = __builtin_amdgcn_mfma_f32_16x16x32_bf16(phi[n], ehi, acc, 0, 0, 0);
        acc = __builtin_amdgcn_mfma_f32_16x16x32_bf16(plo[n], ehi, acc, 0, 0, 0);
        acc = __builtin_amdgcn_mfma_f32_16x16x32_bf16(phi[n], elo, acc, 0, 0, 0);
        s += __builtin_amdgcn_exp2f(acc[0]) + __builtin_amdgcn_exp2f(acc[1]) +
             __builtin_amdgcn_exp2f(acc[2]) + __builtin_amdgcn_exp2f(acc[3]);
    }
    // full 80-cat sum for point (lane&15): reduce over the 4 sub-groups
    s += __shfl_xor(s, 16);
    s += __shfl_xor(s, 32);
    s -= nabs;                       // remove the exactly-1 terms of zero rows
    const float cl = __builtin_amdgcn_logf(s);   // log2
    if (keep && sub == 0) {
        lacc += cl - dl;
        kacc += 1.f;
    }
}

// k_loss v6: 4 independent 16-point groups per wave-iteration (16 chains/SIMD).
template <int BPB>
__global__ __launch_bounds__(256, 4) void k_loss(const float* __restrict__ emb,
                                                 const int* __restrict__ lab,
                                                 const float* __restrict__ protos,
                                                 const float* __restrict__ nabsp,
                                                 float* __restrict__ lossout,
                                                 int Nb) {
    __shared__ float s_red[8];
    const int b = blockIdx.x / BPB;
    const int blk = blockIdx.x % BPB;
    const int t = threadIdx.x;
    const int lane = t & 63;
    const int wave = t >> 6;
    const int lid = lane & 15;   // A: cat-in-tile / B: point / C: point col
    const int sub = lane >> 4;   // k-chunk (A,B) / cat row-quad (C)

    const float* pp = protos + b * NCATP * DIM;
    const float nabs = nabsp[b];
    const float* eb = emb + (size_t)b * Nb * DIM;
    const int* lb = lab + (size_t)b * Nb;
    const float LN2 = 0.6931471805599453f;

    // ---- A fragments (prototypes), built once: 5 tiles x (hi,lo) ----
    short8v phi[5], plo[5];
    #pragma unroll
    for (int n = 0; n < 5; n++) {
        const int cat = n * 16 + lid;
        const float4* qk = (const float4*)(pp + cat * DIM + sub * 8);
        float4 q0 = qk[0], q1 = qk[1];
        float qa[8] = {q0.x, q0.y, q0.z, q0.w, q1.x, q1.y, q1.z, q1.w};
        #pragma unroll
        for (int j = 0; j < 8; j++) {
            float hf;
            phi[n][j] = f2bf_hi(qa[j], &hf);
            plo[n][j] = f2bf(qa[j] - hf);
        }
    }

    float lacc = 0.f, kacc = 0.f;

    #pragma unroll 1
    for (int p0 = (blk * 4 + wave) * 64; p0 < Nb; p0 += BPB * 4 * 64) {
        point_group(p0 + lid,      eb, lb, pp, phi, plo, nabs, sub, lacc, kacc);
        point_group(p0 + 16 + lid, eb, lb, pp, phi, plo, nabs, sub, lacc, kacc);
        point_group(p0 + 32 + lid, eb, lb, pp, phi, plo, nabs, sub, lacc, kacc);
        point_group(p0 + 48 + lid, eb, lb, pp, phi, plo, nabs, sub, lacc, kacc);
    }

    #pragma unroll
    for (int m = 32; m >= 1; m >>= 1) {
        lacc += __shfl_xor(lacc, m);
        kacc += __shfl_xor(kacc, m);
    }
    if (lane == 0) {
        s_red[wave] = lacc;
        s_red[4 + wave] = kacc;
    }
    __syncthreads();
    if (t == 0) {
        float a = s_red[0] + s_red[1] + s_red[2] + s_red[3];
        float k = s_red[4] + s_red[5] + s_red[6] + s_red[7];
        unsafeAtomicAdd(lossout + b, LN2 * a);      // WS_LOSS (ln-space)
        unsafeAtomicAdd(lossout + BNUM + b, k);     // WS_KEEP
    }
}

__global__ void k_final(const float* __restrict__ ws, float* __restrict__ out) {
    if (threadIdx.x == 0 && blockIdx.x == 0) {
        float s = 0.f;
        for (int b = 0; b < BNUM; b++) {
            float l = ws[WS_LOSS + b];
            float k = ws[WS_KEEP + b];
            s += l / fmaxf(k, 1.0f);
        }
        out[0] = SEG_W * (s / BNUM);
    }
}

extern "C" void kernel_launch(void* const* d_in, const int* in_sizes, int n_in,
                              void* d_out, int out_size, void* d_ws, size_t ws_size,
                              hipStream_t stream) {
    const float* emb = (const float*)d_in[0];
    const int* lab = (const int*)d_in[1];
    float* ws = (float*)d_ws;
    float* out = (float*)d_out;
    const int total_pts = in_sizes[1];
    const int Nb = total_pts / BNUM;

    hipMemsetAsync(d_ws, 0, WS_TOTAL * sizeof(float), stream);
    constexpr int BPB_ACC = 192;   // 768 blocks -> 3 blocks/CU (LDS 42KB/block)
    constexpr int BPB_LOSS = 256;  // 1024 blocks, 4 iters/wave of 4x16 points
    k_accum<BPB_ACC><<<dim3(BNUM * BPB_ACC), dim3(256), 0, stream>>>(emb, lab, ws, Nb);
    k_proto<<<dim3(BNUM), dim3(256), 0, stream>>>(ws);
    k_loss<BPB_LOSS><<<dim3(BNUM * BPB_LOSS), dim3(256), 0, stream>>>(
        emb, lab, ws + WS_PROT, ws + WS_NABS, ws + WS_LOSS, Nb);
    k_final<<<1, 64, 0, stream>>>(ws, out);
}

// Round 7
// 137.038 us; speedup vs baseline: 1.6737x; 1.6737x over previous
//
#include <hip/hip_runtime.h>
#include <hip/hip_bf16.h>

#define NCAT 72
#define NCATP 80          // padded to 5 MFMA cat-tiles of 16
#define DIM 32
#define BNUM 4
#define TEMP_INV (1.0f / 0.07f)
#define SEG_W 10.0f

// ws layout (floats):
#define WS_SUMS 0         // [4][72][32]
#define WS_CNTS 9216      // [4][72]
#define WS_PROT 9504      // [4][80][32]  normalized prototypes, PADDED, absent/missing rows ZERO
#define WS_NABS 19744     // [4]          count of zero rows (exp2 contributes exactly 1 each)
#define WS_LOSS 19748     // [4]
#define WS_KEEP 19752     // [4]
#define WS_TOTAL 19756

typedef __attribute__((ext_vector_type(8))) short short8v;   // 8 bf16
typedef __attribute__((ext_vector_type(4))) float f32x4;

__device__ __forceinline__ bool is_missing(int c) {
    return (c == 13) | (c == 53) | (c == 61);
}

// float -> bf16(RNE) bits, and the fp32 value of that bf16 (for lo-split)
__device__ __forceinline__ short f2bf_hi(float f, float* hi_f) {
    unsigned u = __float_as_uint(f);
    unsigned r = u + 0x7FFFu + ((u >> 16) & 1u);
    *hi_f = __uint_as_float(r & 0xFFFF0000u);
    return (short)(r >> 16);
}
__device__ __forceinline__ short f2bf(float f) {
    unsigned u = __float_as_uint(f);
    unsigned r = u + 0x7FFFu + ((u >> 16) & 1u);
    return (short)(r >> 16);
}

// k_accum v2 (REVERTED from v3/onehot-MFMA).
// R6 post-mortem: onehot-MFMA was 3.7x WORSE (177.9us, VALUBusy 79%,
// MfmaUtil 12.6%) -- A-fragment construction needs ~300+ VALU instrs per
// 32 points (per-tile cndmask, norm shuffles, bf16 splits) plus strided
// 4B loads; the MFMA never was segment-sum's cost. v2's masked-RMW commit
// (~48us) stands: per-wave private LDS accumulators, 8 exec-masked float4
// read-add-write steps, software-pipelined global loads.
template <int BPB>
__global__ __launch_bounds__(256) void k_accum(const float* __restrict__ emb,
                                               const int* __restrict__ lab,
                                               float* __restrict__ ws, int Nb) {
    __shared__ float s_acc[4][NCAT][DIM];  // per-wave private, rows 128B-aligned
    __shared__ float s_cnt[4][NCAT];
    const int t = threadIdx.x;
    const int b = blockIdx.x / BPB;
    const int blk = blockIdx.x % BPB;
    const int w = t >> 6;         // wave 0..3
    const int g = (t >> 3) & 7;   // point-slot within wave
    const int sub = t & 7;        // float4 index within point
    const int pofs = t >> 3;      // 0..31: point slot within block

    for (int i = t; i < 4 * NCAT * DIM; i += 256) ((float*)s_acc)[i] = 0.f;
    for (int i = t; i < 4 * NCAT; i += 256) ((float*)s_cnt)[i] = 0.f;
    __syncthreads();

    float* accw = &s_acc[w][0][0];
    const float* eb = emb + (size_t)b * Nb * DIM;
    const int* lb = lab + (size_t)b * Nb;

    int p = blk * 32 + pofs;
    int l_cur = lb[p];
    float4 v_cur = ((const float4*)(eb + (size_t)p * DIM))[sub];

    for (int p0 = blk * 32; p0 < Nb; p0 += BPB * 32) {
        const int pn = p0 + BPB * 32 + pofs;
        int l_nxt = -1;
        float4 v_nxt = make_float4(0.f, 0.f, 0.f, 0.f);
        if (pn < Nb) {
            l_nxt = lb[pn];
            v_nxt = ((const float4*)(eb + (size_t)pn * DIM))[sub];
        }

        float ss = v_cur.x * v_cur.x + v_cur.y * v_cur.y +
                   v_cur.z * v_cur.z + v_cur.w * v_cur.w;
        ss += __shfl_xor(ss, 1);
        ss += __shfl_xor(ss, 2);
        ss += __shfl_xor(ss, 4);
        const float inv = 1.0f / fmaxf(sqrtf(ss), 1e-12f);
        const bool valid = (l_cur >= 0);
        const int lc = min(max(l_cur, 0), NCAT - 1);
        float4 u;
        u.x = v_cur.x * inv; u.y = v_cur.y * inv;
        u.z = v_cur.z * inv; u.w = v_cur.w * inv;

        if (valid && sub == 0) unsafeAtomicAdd(&s_cnt[w][lc], 1.0f);

        float* rowp = accw + lc * DIM + sub * 4;
        #pragma unroll
        for (int k = 0; k < 8; k++) {
            if (g == k && valid) {
                float4* r4 = (float4*)rowp;
                float4 o = *r4;
                o.x += u.x; o.y += u.y; o.z += u.z; o.w += u.w;
                *r4 = o;
            }
            __builtin_amdgcn_sched_barrier(0);  // keep the 8 steps distinct & ordered
        }

        l_cur = l_nxt;
        v_cur = v_nxt;
    }
    __syncthreads();

    float* gs = ws + WS_SUMS + b * NCAT * DIM;
    const float* sa = (const float*)s_acc;
    for (int i = t; i < NCAT * DIM; i += 256) {
        float val = sa[i] + sa[NCAT * DIM + i] +
                    sa[2 * NCAT * DIM + i] + sa[3 * NCAT * DIM + i];
        if (val != 0.f) unsafeAtomicAdd(&gs[i], val);
    }
    if (t < NCAT) {
        float c = s_cnt[0][t] + s_cnt[1][t] + s_cnt[2][t] + s_cnt[3][t];
        if (c != 0.f) unsafeAtomicAdd(ws + WS_CNTS + b * NCAT + t, c);
    }
}

// One block per batch: normalize sums -> prototypes (padded, absent rows ZERO)
// and store n_absent = count of zero rows (incl. 8 pad rows).
__global__ __launch_bounds__(256) void k_proto(float* __restrict__ ws) {
    const int b = blockIdx.x;
    __shared__ float s_np;
    if (threadIdx.x == 0) s_np = 0.f;
    __syncthreads();
    const float* gs = ws + WS_SUMS + b * NCAT * DIM;
    const float* gc = ws + WS_CNTS + b * NCAT;
    float* gp = ws + WS_PROT + b * NCATP * DIM;
    const int dd = threadIdx.x & 31;
    const int r0 = threadIdx.x >> 5;
    for (int c = r0; c < NCAT; c += 8) {
        float cnt = gc[c];
        float val = gs[c * DIM + dd] / fmaxf(cnt, 1.0f);
        float ss = val * val;
        #pragma unroll
        for (int m = 16; m >= 1; m >>= 1) ss += __shfl_xor(ss, m);
        float inv = 1.0f / fmaxf(sqrtf(ss), 1e-12f);
        const bool present = (cnt > 0.f) && !is_missing(c);
        gp[c * DIM + dd] = present ? val * inv : 0.f;  // zero row -> exp2 term exactly 1
        if (dd == 0) unsafeAtomicAdd(&s_np, present ? 1.f : 0.f);
        // rows 72..79 remain zero from the memset
    }
    __syncthreads();
    if (threadIdx.x == 0) ws[WS_NABS + b] = (float)NCATP - s_np;
}

// One 16-point group: load, normalize, label-dot (exact fp32), bf16x3 MFMA
// against the wave-resident prototype fragments, softmax-sum, accumulate.
__device__ __forceinline__ void point_group(
    int pt, const float* __restrict__ eb, const int* __restrict__ lb,
    const float* __restrict__ pp, const short8v phi[5], const short8v plo[5],
    float nabs, int sub, float& lacc, float& kacc)
{
    const float LOG2E = 1.4426950408889634f;
    const int l = lb[pt];
    const int lc = min(max(l, 0), NCAT - 1);

    const float4* ep = (const float4*)(eb + (size_t)pt * DIM + sub * 8);
    float4 a0 = ep[0], a1 = ep[1];

    float ss = a0.x * a0.x + a0.y * a0.y + a0.z * a0.z + a0.w * a0.w +
               a1.x * a1.x + a1.y * a1.y + a1.z * a1.z + a1.w * a1.w;
    ss += __shfl_xor(ss, 16);
    ss += __shfl_xor(ss, 32);
    const float sca = (TEMP_INV * LOG2E) / fmaxf(sqrtf(ss), 1e-12f);
    a0.x *= sca; a0.y *= sca; a0.z *= sca; a0.w *= sca;
    a1.x *= sca; a1.y *= sca; a1.z *= sca; a1.w *= sca;

    // label logit (log2 units), exact fp32
    const float4* qk = (const float4*)(pp + lc * DIM + sub * 8);
    float4 q0 = qk[0], q1 = qk[1];
    float dl = q0.x * a0.x + q0.y * a0.y + q0.z * a0.z + q0.w * a0.w +
               q1.x * a1.x + q1.y * a1.y + q1.z * a1.z + q1.w * a1.w;
    dl += __shfl_xor(dl, 16);
    dl += __shfl_xor(dl, 32);

    const bool keep = (l >= 0) && !is_missing(lc);

    // bf16 hi/lo split of the scaled point (B fragment: col=lane&15=point)
    float ea[8] = {a0.x, a0.y, a0.z, a0.w, a1.x, a1.y, a1.z, a1.w};
    short8v ehi, elo;
    #pragma unroll
    for (int j = 0; j < 8; j++) {
        float hf;
        ehi[j] = f2bf_hi(ea[j], &hf);
        elo[j] = f2bf(ea[j] - hf);
    }

    // 5 cat-tiles: C col=point(lane&15), row=cat-in-tile=(sub*4+reg)
    float s = 0.f;
    #pragma unroll
    for (int n = 0; n < 5; n++) {
        f32x4 acc = {0.f, 0.f, 0.f, 0.f};
        acc = __builtin_amdgcn_mfma_f32_16x16x32_bf16(phi[n], ehi, acc, 0, 0, 0);
        acc = __builtin_amdgcn_mfma_f32_16x16x32_bf16(plo[n], ehi, acc, 0, 0, 0);
        acc = __builtin_amdgcn_mfma_f32_16x16x32_bf16(phi[n], elo, acc, 0, 0, 0);
        s += __builtin_amdgcn_exp2f(acc[0]) + __builtin_amdgcn_exp2f(acc[1]) +
             __builtin_amdgcn_exp2f(acc[2]) + __builtin_amdgcn_exp2f(acc[3]);
    }
    // full 80-cat sum for point (lane&15): reduce over the 4 sub-groups
    s += __shfl_xor(s, 16);
    s += __shfl_xor(s, 32);
    s -= nabs;                       // remove the exactly-1 terms of zero rows
    const float cl = __builtin_amdgcn_logf(s);   // log2
    if (keep && sub == 0) {
        lacc += cl - dl;
        kacc += 1.f;
    }
}

// k_loss v6: 4 independent 16-point groups per wave-iteration (16 chains/SIMD).
// R6: confirmed ~40-45us (total-minus-accum accounting). KEPT.
template <int BPB>
__global__ __launch_bounds__(256, 4) void k_loss(const float* __restrict__ emb,
                                                 const int* __restrict__ lab,
                                                 const float* __restrict__ protos,
                                                 const float* __restrict__ nabsp,
                                                 float* __restrict__ lossout,
                                                 int Nb) {
    __shared__ float s_red[8];
    const int b = blockIdx.x / BPB;
    const int blk = blockIdx.x % BPB;
    const int t = threadIdx.x;
    const int lane = t & 63;
    const int wave = t >> 6;
    const int lid = lane & 15;   // A: cat-in-tile / B: point / C: point col
    const int sub = lane >> 4;   // k-chunk (A,B) / cat row-quad (C)

    const float* pp = protos + b * NCATP * DIM;
    const float nabs = nabsp[b];
    const float* eb = emb + (size_t)b * Nb * DIM;
    const int* lb = lab + (size_t)b * Nb;
    const float LN2 = 0.6931471805599453f;

    // ---- A fragments (prototypes), built once: 5 tiles x (hi,lo) ----
    short8v phi[5], plo[5];
    #pragma unroll
    for (int n = 0; n < 5; n++) {
        const int cat = n * 16 + lid;
        const float4* qk = (const float4*)(pp + cat * DIM + sub * 8);
        float4 q0 = qk[0], q1 = qk[1];
        float qa[8] = {q0.x, q0.y, q0.z, q0.w, q1.x, q1.y, q1.z, q1.w};
        #pragma unroll
        for (int j = 0; j < 8; j++) {
            float hf;
            phi[n][j] = f2bf_hi(qa[j], &hf);
            plo[n][j] = f2bf(qa[j] - hf);
        }
    }

    float lacc = 0.f, kacc = 0.f;

    #pragma unroll 1
    for (int p0 = (blk * 4 + wave) * 64; p0 < Nb; p0 += BPB * 4 * 64) {
        point_group(p0 + lid,      eb, lb, pp, phi, plo, nabs, sub, lacc, kacc);
        point_group(p0 + 16 + lid, eb, lb, pp, phi, plo, nabs, sub, lacc, kacc);
        point_group(p0 + 32 + lid, eb, lb, pp, phi, plo, nabs, sub, lacc, kacc);
        point_group(p0 + 48 + lid, eb, lb, pp, phi, plo, nabs, sub, lacc, kacc);
    }

    #pragma unroll
    for (int m = 32; m >= 1; m >>= 1) {
        lacc += __shfl_xor(lacc, m);
        kacc += __shfl_xor(kacc, m);
    }
    if (lane == 0) {
        s_red[wave] = lacc;
        s_red[4 + wave] = kacc;
    }
    __syncthreads();
    if (t == 0) {
        float a = s_red[0] + s_red[1] + s_red[2] + s_red[3];
        float k = s_red[4] + s_red[5] + s_red[6] + s_red[7];
        unsafeAtomicAdd(lossout + b, LN2 * a);      // WS_LOSS (ln-space)
        unsafeAtomicAdd(lossout + BNUM + b, k);     // WS_KEEP
    }
}

__global__ void k_final(const float* __restrict__ ws, float* __restrict__ out) {
    if (threadIdx.x == 0 && blockIdx.x == 0) {
        float s = 0.f;
        for (int b = 0; b < BNUM; b++) {
            float l = ws[WS_LOSS + b];
            float k = ws[WS_KEEP + b];
            s += l / fmaxf(k, 1.0f);
        }
        out[0] = SEG_W * (s / BNUM);
    }
}

extern "C" void kernel_launch(void* const* d_in, const int* in_sizes, int n_in,
                              void* d_out, int out_size, void* d_ws, size_t ws_size,
                              hipStream_t stream) {
    const float* emb = (const float*)d_in[0];
    const int* lab = (const int*)d_in[1];
    float* ws = (float*)d_ws;
    float* out = (float*)d_out;
    const int total_pts = in_sizes[1];
    const int Nb = total_pts / BNUM;

    hipMemsetAsync(d_ws, 0, WS_TOTAL * sizeof(float), stream);
    constexpr int BPB_ACC = 256;   // 1024 blocks -> 4 blocks/CU (LDS 38KB/block)
    constexpr int BPB_LOSS = 256;  // 1024 blocks, 4 iters/wave of 4x16 points
    k_accum<BPB_ACC><<<dim3(BNUM * BPB_ACC), dim3(256), 0, stream>>>(emb, lab, ws, Nb);
    k_proto<<<dim3(BNUM), dim3(256), 0, stream>>>(ws);
    k_loss<BPB_LOSS><<<dim3(BNUM * BPB_LOSS), dim3(256), 0, stream>>>(
        emb, lab, ws + WS_PROT, ws + WS_NABS, ws + WS_LOSS, Nb);
    k_final<<<1, 64, 0, stream>>>(ws, out);
}

// Round 8
// 129.692 us; speedup vs baseline: 1.7685x; 1.0566x over previous
//
#include <hip/hip_runtime.h>
#include <hip/hip_bf16.h>

#define NCAT 72
#define NCATP 80          // padded to 5 MFMA cat-tiles of 16
#define DIM 32
#define BNUM 4
#define TEMP_INV (1.0f / 0.07f)
#define SEG_W 10.0f

// ws layout (floats):
#define WS_SUMS 0         // [4][72][32]
#define WS_CNTS 9216      // [4][72]
#define WS_PROT 9504      // [4][80][32]  normalized prototypes, PADDED, absent/missing rows ZERO
#define WS_NABS 19744     // [4]          count of zero rows (exp2 contributes exactly 1 each)
#define WS_LOSS 19748     // [4]
#define WS_KEEP 19752     // [4]
#define WS_TOTAL 19756

typedef __attribute__((ext_vector_type(8))) short short8v;   // 8 bf16
typedef __attribute__((ext_vector_type(4))) float f32x4;
typedef __attribute__((ext_vector_type(4))) unsigned u32x4;

__device__ __forceinline__ bool is_missing(int c) {
    return (c == 13) | (c == 53) | (c == 61);
}

// float -> bf16(RNE) bits, and the fp32 value of that bf16 (for lo-split)
__device__ __forceinline__ short f2bf_hi(float f, float* hi_f) {
    unsigned u = __float_as_uint(f);
    unsigned r = u + 0x7FFFu + ((u >> 16) & 1u);
    *hi_f = __uint_as_float(r & 0xFFFF0000u);
    return (short)(r >> 16);
}
__device__ __forceinline__ short f2bf(float f) {
    unsigned u = __float_as_uint(f);
    unsigned r = u + 0x7FFFu + ((u >> 16) & 1u);
    return (short)(r >> 16);
}

// packed f32x2 -> bf16x2 (low16 = bf16(a)); no builtin on gfx950 (m240) ->
// thin non-volatile asm so the scheduler can move/CSE it.
__device__ __forceinline__ unsigned cvtpk_bf16(float a, float b) {
    unsigned r;
    asm("v_cvt_pk_bf16_f32 %0, %1, %2" : "=v"(r) : "v"(a), "v"(b));
    return r;
}

// k_accum v2 (R6: reverted here from onehot-MFMA, which was 3.7x worse --
// VALU-bound fragment construction, MfmaUtil 12.6%). Masked-RMW commit:
// per-wave private LDS accumulators, 8 exec-masked float4 read-add-write
// steps (sched_barrier'd), software-pipelined global loads.
template <int BPB>
__global__ __launch_bounds__(256) void k_accum(const float* __restrict__ emb,
                                               const int* __restrict__ lab,
                                               float* __restrict__ ws, int Nb) {
    __shared__ float s_acc[4][NCAT][DIM];  // per-wave private, rows 128B-aligned
    __shared__ float s_cnt[4][NCAT];
    const int t = threadIdx.x;
    const int b = blockIdx.x / BPB;
    const int blk = blockIdx.x % BPB;
    const int w = t >> 6;         // wave 0..3
    const int g = (t >> 3) & 7;   // point-slot within wave
    const int sub = t & 7;        // float4 index within point
    const int pofs = t >> 3;      // 0..31: point slot within block

    for (int i = t; i < 4 * NCAT * DIM; i += 256) ((float*)s_acc)[i] = 0.f;
    for (int i = t; i < 4 * NCAT; i += 256) ((float*)s_cnt)[i] = 0.f;
    __syncthreads();

    float* accw = &s_acc[w][0][0];
    const float* eb = emb + (size_t)b * Nb * DIM;
    const int* lb = lab + (size_t)b * Nb;

    int p = blk * 32 + pofs;
    int l_cur = lb[p];
    float4 v_cur = ((const float4*)(eb + (size_t)p * DIM))[sub];

    for (int p0 = blk * 32; p0 < Nb; p0 += BPB * 32) {
        const int pn = p0 + BPB * 32 + pofs;
        int l_nxt = -1;
        float4 v_nxt = make_float4(0.f, 0.f, 0.f, 0.f);
        if (pn < Nb) {
            l_nxt = lb[pn];
            v_nxt = ((const float4*)(eb + (size_t)pn * DIM))[sub];
        }

        float ss = v_cur.x * v_cur.x + v_cur.y * v_cur.y +
                   v_cur.z * v_cur.z + v_cur.w * v_cur.w;
        ss += __shfl_xor(ss, 1);
        ss += __shfl_xor(ss, 2);
        ss += __shfl_xor(ss, 4);
        const float inv = 1.0f / fmaxf(sqrtf(ss), 1e-12f);
        const bool valid = (l_cur >= 0);
        const int lc = min(max(l_cur, 0), NCAT - 1);
        float4 u;
        u.x = v_cur.x * inv; u.y = v_cur.y * inv;
        u.z = v_cur.z * inv; u.w = v_cur.w * inv;

        if (valid && sub == 0) unsafeAtomicAdd(&s_cnt[w][lc], 1.0f);

        float* rowp = accw + lc * DIM + sub * 4;
        #pragma unroll
        for (int k = 0; k < 8; k++) {
            if (g == k && valid) {
                float4* r4 = (float4*)rowp;
                float4 o = *r4;
                o.x += u.x; o.y += u.y; o.z += u.z; o.w += u.w;
                *r4 = o;
            }
            __builtin_amdgcn_sched_barrier(0);  // keep the 8 steps distinct & ordered
        }

        l_cur = l_nxt;
        v_cur = v_nxt;
    }
    __syncthreads();

    float* gs = ws + WS_SUMS + b * NCAT * DIM;
    const float* sa = (const float*)s_acc;
    for (int i = t; i < NCAT * DIM; i += 256) {
        float val = sa[i] + sa[NCAT * DIM + i] +
                    sa[2 * NCAT * DIM + i] + sa[3 * NCAT * DIM + i];
        if (val != 0.f) unsafeAtomicAdd(&gs[i], val);
    }
    if (t < NCAT) {
        float c = s_cnt[0][t] + s_cnt[1][t] + s_cnt[2][t] + s_cnt[3][t];
        if (c != 0.f) unsafeAtomicAdd(ws + WS_CNTS + b * NCAT + t, c);
    }
}

// One block per batch: normalize sums -> prototypes (padded, absent rows ZERO)
// and store n_absent = count of zero rows (incl. 8 pad rows).
__global__ __launch_bounds__(256) void k_proto(float* __restrict__ ws) {
    const int b = blockIdx.x;
    __shared__ float s_np;
    if (threadIdx.x == 0) s_np = 0.f;
    __syncthreads();
    const float* gs = ws + WS_SUMS + b * NCAT * DIM;
    const float* gc = ws + WS_CNTS + b * NCAT;
    float* gp = ws + WS_PROT + b * NCATP * DIM;
    const int dd = threadIdx.x & 31;
    const int r0 = threadIdx.x >> 5;
    for (int c = r0; c < NCAT; c += 8) {
        float cnt = gc[c];
        float val = gs[c * DIM + dd] / fmaxf(cnt, 1.0f);
        float ss = val * val;
        #pragma unroll
        for (int m = 16; m >= 1; m >>= 1) ss += __shfl_xor(ss, m);
        float inv = 1.0f / fmaxf(sqrtf(ss), 1e-12f);
        const bool present = (cnt > 0.f) && !is_missing(c);
        gp[c * DIM + dd] = present ? val * inv : 0.f;  // zero row -> exp2 term exactly 1
        if (dd == 0) unsafeAtomicAdd(&s_np, present ? 1.f : 0.f);
        // rows 72..79 remain zero from the memset
    }
    __syncthreads();
    if (threadIdx.x == 0) ws[WS_NABS + b] = (float)NCATP - s_np;
}

// k_loss v7 point group.
// R7 changes vs v6:
//  (a) label logit extracted from the MFMA C-fragment instead of a 128B/lane
//      scattered gather of proto[lc]: holder lane = ((lc&15)>>2)*16 + point,
//      reg = lc&3, tile = lc>>4. Kills the per-group L1 gather serialization
//      (the shared-resource cost 4-way ILP couldn't hide) and makes the label
//      term come from the SAME logit matrix as the softmax sum (errors cancel).
//  (b) bf16 hi/lo split via v_cvt_pk_bf16_f32 pairs (self-correcting split:
//      lo = residual of hi under any deterministic rounding).
__device__ __forceinline__ void point_group(
    int pt, const float* __restrict__ eb, const int* __restrict__ lb,
    const short8v phi[5], const short8v plo[5],
    float nabs, int sub, float& lacc, float& dacc, float& kacc)
{
    const float LOG2E = 1.4426950408889634f;
    const int l = lb[pt];
    const int lc = min(max(l, 0), NCAT - 1);

    const float4* ep = (const float4*)(eb + (size_t)pt * DIM + sub * 8);
    float4 a0 = ep[0], a1 = ep[1];

    float ss = a0.x * a0.x + a0.y * a0.y + a0.z * a0.z + a0.w * a0.w +
               a1.x * a1.x + a1.y * a1.y + a1.z * a1.z + a1.w * a1.w;
    ss += __shfl_xor(ss, 16);
    ss += __shfl_xor(ss, 32);
    const float sca = (TEMP_INV * LOG2E) / fmaxf(sqrtf(ss), 1e-12f);
    a0.x *= sca; a0.y *= sca; a0.z *= sca; a0.w *= sca;
    a1.x *= sca; a1.y *= sca; a1.z *= sca; a1.w *= sca;

    const bool keep = (l >= 0) && !is_missing(lc);
    const int ltile = lc >> 4;                         // which 16-cat tile
    const bool qm = keep && (((lc >> 2) & 3) == sub);  // my sub holds the label row-quad

    // bf16 hi/lo split of the scaled point via cvt_pk (B frag: col=lane&15=point)
    float ea[8] = {a0.x, a0.y, a0.z, a0.w, a1.x, a1.y, a1.z, a1.w};
    u32x4 hw, lw;
    #pragma unroll
    for (int j = 0; j < 4; j++) {
        const float x0 = ea[2 * j], x1 = ea[2 * j + 1];
        const unsigned h = cvtpk_bf16(x0, x1);
        const float h0 = __uint_as_float(h << 16);
        const float h1 = __uint_as_float(h & 0xFFFF0000u);
        hw[j] = h;
        lw[j] = cvtpk_bf16(x0 - h0, x1 - h1);
    }
    const short8v ehi = __builtin_bit_cast(short8v, hw);
    const short8v elo = __builtin_bit_cast(short8v, lw);

    // 5 cat-tiles: C col=point(lane&15), row=cat-in-tile=(sub*4+reg)
    float s = 0.f;
    #pragma unroll
    for (int n = 0; n < 5; n++) {
        f32x4 acc = {0.f, 0.f, 0.f, 0.f};
        acc = __builtin_amdgcn_mfma_f32_16x16x32_bf16(phi[n], ehi, acc, 0, 0, 0);
        acc = __builtin_amdgcn_mfma_f32_16x16x32_bf16(plo[n], ehi, acc, 0, 0, 0);
        acc = __builtin_amdgcn_mfma_f32_16x16x32_bf16(phi[n], elo, acc, 0, 0, 0);
        s += __builtin_amdgcn_exp2f(acc[0]) + __builtin_amdgcn_exp2f(acc[1]) +
             __builtin_amdgcn_exp2f(acc[2]) + __builtin_amdgcn_exp2f(acc[3]);
        if (qm && ltile == n) {                 // label logit straight from C
            const float d01 = (lc & 1) ? acc[1] : acc[0];
            const float d23 = (lc & 1) ? acc[3] : acc[2];
            dacc += (lc & 2) ? d23 : d01;
        }
    }
    // full 80-cat sum for point (lane&15): reduce over the 4 sub-groups
    s += __shfl_xor(s, 16);
    s += __shfl_xor(s, 32);
    s -= nabs;                       // remove the exactly-1 terms of zero rows
    const float cl = __builtin_amdgcn_logf(s);   // log2
    if (keep && sub == 0) {
        lacc += cl;
        kacc += 1.f;
    }
}

// k_loss v7: 4 independent 16-point groups per wave-iteration; gather-free
// label logit; cvt_pk split.
template <int BPB>
__global__ __launch_bounds__(256, 4) void k_loss(const float* __restrict__ emb,
                                                 const int* __restrict__ lab,
                                                 const float* __restrict__ protos,
                                                 const float* __restrict__ nabsp,
                                                 float* __restrict__ lossout,
                                                 int Nb) {
    __shared__ float s_red[8];
    const int b = blockIdx.x / BPB;
    const int blk = blockIdx.x % BPB;
    const int t = threadIdx.x;
    const int lane = t & 63;
    const int wave = t >> 6;
    const int lid = lane & 15;   // A: cat-in-tile / B: point / C: point col
    const int sub = lane >> 4;   // k-chunk (A,B) / cat row-quad (C)

    const float* pp = protos + b * NCATP * DIM;
    const float nabs = nabsp[b];
    const float* eb = emb + (size_t)b * Nb * DIM;
    const int* lb = lab + (size_t)b * Nb;
    const float LN2 = 0.6931471805599453f;

    // ---- A fragments (prototypes), built once: 5 tiles x (hi,lo) ----
    short8v phi[5], plo[5];
    #pragma unroll
    for (int n = 0; n < 5; n++) {
        const int cat = n * 16 + lid;
        const float4* qk = (const float4*)(pp + cat * DIM + sub * 8);
        float4 q0 = qk[0], q1 = qk[1];
        float qa[8] = {q0.x, q0.y, q0.z, q0.w, q1.x, q1.y, q1.z, q1.w};
        #pragma unroll
        for (int j = 0; j < 8; j++) {
            float hf;
            phi[n][j] = f2bf_hi(qa[j], &hf);
            plo[n][j] = f2bf(qa[j] - hf);
        }
    }

    float lacc = 0.f, dacc = 0.f, kacc = 0.f;

    #pragma unroll 1
    for (int p0 = (blk * 4 + wave) * 64; p0 < Nb; p0 += BPB * 4 * 64) {
        point_group(p0 + lid,      eb, lb, phi, plo, nabs, sub, lacc, dacc, kacc);
        point_group(p0 + 16 + lid, eb, lb, phi, plo, nabs, sub, lacc, dacc, kacc);
        point_group(p0 + 32 + lid, eb, lb, phi, plo, nabs, sub, lacc, dacc, kacc);
        point_group(p0 + 48 + lid, eb, lb, phi, plo, nabs, sub, lacc, dacc, kacc);
    }

    // v = sum(log2 sums) - sum(label logits); k = kept count
    float v = lacc - dacc;
    #pragma unroll
    for (int m = 32; m >= 1; m >>= 1) {
        v += __shfl_xor(v, m);
        kacc += __shfl_xor(kacc, m);
    }
    if (lane == 0) {
        s_red[wave] = v;
        s_red[4 + wave] = kacc;
    }
    __syncthreads();
    if (t == 0) {
        float a = s_red[0] + s_red[1] + s_red[2] + s_red[3];
        float k = s_red[4] + s_red[5] + s_red[6] + s_red[7];
        unsafeAtomicAdd(lossout + b, LN2 * a);      // WS_LOSS (ln-space)
        unsafeAtomicAdd(lossout + BNUM + b, k);     // WS_KEEP
    }
}

__global__ void k_final(const float* __restrict__ ws, float* __restrict__ out) {
    if (threadIdx.x == 0 && blockIdx.x == 0) {
        float s = 0.f;
        for (int b = 0; b < BNUM; b++) {
            float l = ws[WS_LOSS + b];
            float k = ws[WS_KEEP + b];
            s += l / fmaxf(k, 1.0f);
        }
        out[0] = SEG_W * (s / BNUM);
    }
}

extern "C" void kernel_launch(void* const* d_in, const int* in_sizes, int n_in,
                              void* d_out, int out_size, void* d_ws, size_t ws_size,
                              hipStream_t stream) {
    const float* emb = (const float*)d_in[0];
    const int* lab = (const int*)d_in[1];
    float* ws = (float*)d_ws;
    float* out = (float*)d_out;
    const int total_pts = in_sizes[1];
    const int Nb = total_pts / BNUM;

    hipMemsetAsync(d_ws, 0, WS_TOTAL * sizeof(float), stream);
    constexpr int BPB_ACC = 256;   // 1024 blocks -> 4 blocks/CU (LDS 38KB/block)
    constexpr int BPB_LOSS = 256;  // 1024 blocks, 4 iters/wave of 4x16 points
    k_accum<BPB_ACC><<<dim3(BNUM * BPB_ACC), dim3(256), 0, stream>>>(emb, lab, ws, Nb);
    k_proto<<<dim3(BNUM), dim3(256), 0, stream>>>(ws);
    k_loss<BPB_LOSS><<<dim3(BNUM * BPB_LOSS), dim3(256), 0, stream>>>(
        emb, lab, ws + WS_PROT, ws + WS_NABS, ws + WS_LOSS, Nb);
    k_final<<<1, 64, 0, stream>>>(ws, out);
}

// Round 9
// 114.179 us; speedup vs baseline: 2.0087x; 1.1359x over previous
//
#include <hip/hip_runtime.h>
#include <hip/hip_bf16.h>

#define NCAT 72
#define NCATP 80          // padded to 5 MFMA cat-tiles of 16
#define DIM 32
#define ROWS 36           // k_accum LDS row stride: 144B, 16B-aligned, 4-bank rotation/label
#define BNUM 4
#define TEMP_INV (1.0f / 0.07f)
#define SEG_W 10.0f

// ws layout (floats):
#define WS_SUMS 0         // [4][72][32]
#define WS_CNTS 9216      // [4][72]
#define WS_PROT 9504      // [4][80][32]  normalized prototypes, PADDED, absent/missing rows ZERO
#define WS_NABS 19744     // [4]          count of zero rows (exp2 contributes exactly 1 each)
#define WS_LOSS 19748     // [4]
#define WS_KEEP 19752     // [4]
#define WS_TOTAL 19756

typedef __attribute__((ext_vector_type(8))) short short8v;   // 8 bf16
typedef __attribute__((ext_vector_type(4))) float f32x4;
typedef __attribute__((ext_vector_type(4))) unsigned u32x4;

__device__ __forceinline__ bool is_missing(int c) {
    return (c == 13) | (c == 53) | (c == 61);
}

// float -> bf16(RNE) bits, and the fp32 value of that bf16 (for lo-split)
__device__ __forceinline__ short f2bf_hi(float f, float* hi_f) {
    unsigned u = __float_as_uint(f);
    unsigned r = u + 0x7FFFu + ((u >> 16) & 1u);
    *hi_f = __uint_as_float(r & 0xFFFF0000u);
    return (short)(r >> 16);
}
__device__ __forceinline__ short f2bf(float f) {
    unsigned u = __float_as_uint(f);
    unsigned r = u + 0x7FFFu + ((u >> 16) & 1u);
    return (short)(r >> 16);
}

// packed f32x2 -> bf16x2 (low16 = bf16(a)); no builtin on gfx950 (m240) ->
// thin non-volatile asm so the scheduler can move/CSE it.
__device__ __forceinline__ unsigned cvtpk_bf16(float a, float b) {
    unsigned r;
    asm("v_cvt_pk_bf16_f32 %0, %1, %2" : "=v"(r) : "v"(a), "v"(b));
    return r;
}

// k_accum v4 (collision-resolved commit).
// R8 diagnosis: v2's always-8-step serialized RMW chain issues ~17 DS
// wave-instrs / 32-pt iteration -> DS-issue-bound (~48us vs 21us HBM floor).
// But ~68% of iterations have NO label collision among the wave's 8 slots.
// v4: probe+ballot rounds -- unfinished slot-leaders write slot-id to
// probe[label], read back; winners (unique label this round) commit their
// float4 rows CONCURRENTLY (1 ds_read + 1 ds_write, 64 lanes), losers
// retry. Expected rounds ~1.4 -> ~7 DS ops/iter. Row stride 36 floats
// (16B-aligned, 4-bank rotation/label) avoids the all-rows-bank-0 conflict.
// asm memory clobber per round blocks CSE of the row re-read (another lane
// may have updated the same row between rounds).
template <int BPB>
__global__ __launch_bounds__(256) void k_accum(const float* __restrict__ emb,
                                               const int* __restrict__ lab,
                                               float* __restrict__ ws, int Nb) {
    __shared__ float s_acc[4][NCAT][ROWS];  // per-wave private, 41.5 KB
    __shared__ float s_cnt[4][NCAT];
    __shared__ int   s_prb[4][NCAT];
    const int t = threadIdx.x;
    const int b = blockIdx.x / BPB;
    const int blk = blockIdx.x % BPB;
    const int w = t >> 6;         // wave 0..3
    const int g = (t >> 3) & 7;   // point-slot within wave
    const int sub = t & 7;        // float4 index within point
    const int pofs = t >> 3;      // 0..31: point slot within block

    for (int i = t; i < 4 * NCAT * ROWS; i += 256) ((float*)s_acc)[i] = 0.f;
    for (int i = t; i < 4 * NCAT; i += 256) ((float*)s_cnt)[i] = 0.f;
    __syncthreads();

    float* accw = &s_acc[w][0][0];
    int* prbw = &s_prb[w][0];
    const float* eb = emb + (size_t)b * Nb * DIM;
    const int* lb = lab + (size_t)b * Nb;

    // prologue of the software pipeline (first chunk always in range)
    int p = blk * 32 + pofs;
    int l_cur = lb[p];
    float4 v_cur = ((const float4*)(eb + (size_t)p * DIM))[sub];

    for (int p0 = blk * 32; p0 < Nb; p0 += BPB * 32) {
        // prefetch next chunk while this one computes/commits
        const int pn = p0 + BPB * 32 + pofs;
        int l_nxt = -1;
        float4 v_nxt = make_float4(0.f, 0.f, 0.f, 0.f);
        if (pn < Nb) {
            l_nxt = lb[pn];
            v_nxt = ((const float4*)(eb + (size_t)pn * DIM))[sub];
        }

        float ss = v_cur.x * v_cur.x + v_cur.y * v_cur.y +
                   v_cur.z * v_cur.z + v_cur.w * v_cur.w;
        ss += __shfl_xor(ss, 1);
        ss += __shfl_xor(ss, 2);
        ss += __shfl_xor(ss, 4);
        const float inv = 1.0f / fmaxf(sqrtf(ss), 1e-12f);
        const bool valid = (l_cur >= 0);
        const int lc = min(max(l_cur, 0), NCAT - 1);
        float4 u;
        u.x = v_cur.x * inv; u.y = v_cur.y * inv;
        u.z = v_cur.z * inv; u.w = v_cur.w * inv;

        // counts: one 8-lane ds_add per iteration (atomic handles collisions)
        if (valid && sub == 0) unsafeAtomicAdd(&s_cnt[w][lc], 1.0f);

        float* rowp = accw + lc * ROWS + sub * 4;
        bool active = valid;
        while (__any(active)) {
            asm volatile("" ::: "memory");   // force row re-read each round
            if (active && sub == 0) prbw[lc] = g;          // last-writer-wins
            int win = 0;
            if (active && sub == 0) win = (prbw[lc] == g) ? 1 : 0;
            const unsigned long long wb = __ballot(win);
            const bool iwin = active && ((wb >> (g * 8)) & 1ull);
            if (iwin) {                      // winners have distinct labels
                float4* r4 = (float4*)rowp;
                float4 o = *r4;
                o.x += u.x; o.y += u.y; o.z += u.z; o.w += u.w;
                *r4 = o;
            }
            active = active && !iwin;
        }

        l_cur = l_nxt;
        v_cur = v_nxt;
    }
    __syncthreads();

    // flush: reduce 4 wave-copies, one global atomic per element
    float* gs = ws + WS_SUMS + b * NCAT * DIM;
    for (int i = t; i < NCAT * DIM; i += 256) {
        const int c = i >> 5, d = i & 31;
        float val = s_acc[0][c][d] + s_acc[1][c][d] +
                    s_acc[2][c][d] + s_acc[3][c][d];
        if (val != 0.f) unsafeAtomicAdd(&gs[i], val);
    }
    if (t < NCAT) {
        float c = s_cnt[0][t] + s_cnt[1][t] + s_cnt[2][t] + s_cnt[3][t];
        if (c != 0.f) unsafeAtomicAdd(ws + WS_CNTS + b * NCAT + t, c);
    }
}

// One block per batch: normalize sums -> prototypes (padded, absent rows ZERO)
// and store n_absent = count of zero rows (incl. 8 pad rows).
__global__ __launch_bounds__(256) void k_proto(float* __restrict__ ws) {
    const int b = blockIdx.x;
    __shared__ float s_np;
    if (threadIdx.x == 0) s_np = 0.f;
    __syncthreads();
    const float* gs = ws + WS_SUMS + b * NCAT * DIM;
    const float* gc = ws + WS_CNTS + b * NCAT;
    float* gp = ws + WS_PROT + b * NCATP * DIM;
    const int dd = threadIdx.x & 31;
    const int r0 = threadIdx.x >> 5;
    for (int c = r0; c < NCAT; c += 8) {
        float cnt = gc[c];
        float val = gs[c * DIM + dd] / fmaxf(cnt, 1.0f);
        float ss = val * val;
        #pragma unroll
        for (int m = 16; m >= 1; m >>= 1) ss += __shfl_xor(ss, m);
        float inv = 1.0f / fmaxf(sqrtf(ss), 1e-12f);
        const bool present = (cnt > 0.f) && !is_missing(c);
        gp[c * DIM + dd] = present ? val * inv : 0.f;  // zero row -> exp2 term exactly 1
        if (dd == 0) unsafeAtomicAdd(&s_np, present ? 1.f : 0.f);
        // rows 72..79 remain zero from the memset
    }
    __syncthreads();
    if (threadIdx.x == 0) ws[WS_NABS + b] = (float)NCATP - s_np;
}

// k_loss v7 point group (R7: gather-free label logit from the C fragment;
// cvt_pk hi/lo split). KEPT unchanged for clean A/B this round.
__device__ __forceinline__ void point_group(
    int pt, const float* __restrict__ eb, const int* __restrict__ lb,
    const short8v phi[5], const short8v plo[5],
    float nabs, int sub, float& lacc, float& dacc, float& kacc)
{
    const float LOG2E = 1.4426950408889634f;
    const int l = lb[pt];
    const int lc = min(max(l, 0), NCAT - 1);

    const float4* ep = (const float4*)(eb + (size_t)pt * DIM + sub * 8);
    float4 a0 = ep[0], a1 = ep[1];

    float ss = a0.x * a0.x + a0.y * a0.y + a0.z * a0.z + a0.w * a0.w +
               a1.x * a1.x + a1.y * a1.y + a1.z * a1.z + a1.w * a1.w;
    ss += __shfl_xor(ss, 16);
    ss += __shfl_xor(ss, 32);
    const float sca = (TEMP_INV * LOG2E) / fmaxf(sqrtf(ss), 1e-12f);
    a0.x *= sca; a0.y *= sca; a0.z *= sca; a0.w *= sca;
    a1.x *= sca; a1.y *= sca; a1.z *= sca; a1.w *= sca;

    const bool keep = (l >= 0) && !is_missing(lc);
    const int ltile = lc >> 4;                         // which 16-cat tile
    const bool qm = keep && (((lc >> 2) & 3) == sub);  // my sub holds the label row-quad

    // bf16 hi/lo split of the scaled point via cvt_pk (B frag: col=lane&15=point)
    float ea[8] = {a0.x, a0.y, a0.z, a0.w, a1.x, a1.y, a1.z, a1.w};
    u32x4 hw, lw;
    #pragma unroll
    for (int j = 0; j < 4; j++) {
        const float x0 = ea[2 * j], x1 = ea[2 * j + 1];
        const unsigned h = cvtpk_bf16(x0, x1);
        const float h0 = __uint_as_float(h << 16);
        const float h1 = __uint_as_float(h & 0xFFFF0000u);
        hw[j] = h;
        lw[j] = cvtpk_bf16(x0 - h0, x1 - h1);
    }
    const short8v ehi = __builtin_bit_cast(short8v, hw);
    const short8v elo = __builtin_bit_cast(short8v, lw);

    // 5 cat-tiles: C col=point(lane&15), row=cat-in-tile=(sub*4+reg)
    float s = 0.f;
    #pragma unroll
    for (int n = 0; n < 5; n++) {
        f32x4 acc = {0.f, 0.f, 0.f, 0.f};
        acc = __builtin_amdgcn_mfma_f32_16x16x32_bf16(phi[n], ehi, acc, 0, 0, 0);
        acc = __builtin_amdgcn_mfma_f32_16x16x32_bf16(plo[n], ehi, acc, 0, 0, 0);
        acc = __builtin_amdgcn_mfma_f32_16x16x32_bf16(phi[n], elo, acc, 0, 0, 0);
        s += __builtin_amdgcn_exp2f(acc[0]) + __builtin_amdgcn_exp2f(acc[1]) +
             __builtin_amdgcn_exp2f(acc[2]) + __builtin_amdgcn_exp2f(acc[3]);
        if (qm && ltile == n) {                 // label logit straight from C
            const float d01 = (lc & 1) ? acc[1] : acc[0];
            const float d23 = (lc & 1) ? acc[3] : acc[2];
            dacc += (lc & 2) ? d23 : d01;
        }
    }
    // full 80-cat sum for point (lane&15): reduce over the 4 sub-groups
    s += __shfl_xor(s, 16);
    s += __shfl_xor(s, 32);
    s -= nabs;                       // remove the exactly-1 terms of zero rows
    const float cl = __builtin_amdgcn_logf(s);   // log2
    if (keep && sub == 0) {
        lacc += cl;
        kacc += 1.f;
    }
}

// k_loss v7: 4 independent 16-point groups per wave-iteration; gather-free
// label logit; cvt_pk split.
template <int BPB>
__global__ __launch_bounds__(256, 4) void k_loss(const float* __restrict__ emb,
                                                 const int* __restrict__ lab,
                                                 const float* __restrict__ protos,
                                                 const float* __restrict__ nabsp,
                                                 float* __restrict__ lossout,
                                                 int Nb) {
    __shared__ float s_red[8];
    const int b = blockIdx.x / BPB;
    const int blk = blockIdx.x % BPB;
    const int t = threadIdx.x;
    const int lane = t & 63;
    const int wave = t >> 6;
    const int lid = lane & 15;   // A: cat-in-tile / B: point / C: point col
    const int sub = lane >> 4;   // k-chunk (A,B) / cat row-quad (C)

    const float* pp = protos + b * NCATP * DIM;
    const float nabs = nabsp[b];
    const float* eb = emb + (size_t)b * Nb * DIM;
    const int* lb = lab + (size_t)b * Nb;
    const float LN2 = 0.6931471805599453f;

    // ---- A fragments (prototypes), built once: 5 tiles x (hi,lo) ----
    short8v phi[5], plo[5];
    #pragma unroll
    for (int n = 0; n < 5; n++) {
        const int cat = n * 16 + lid;
        const float4* qk = (const float4*)(pp + cat * DIM + sub * 8);
        float4 q0 = qk[0], q1 = qk[1];
        float qa[8] = {q0.x, q0.y, q0.z, q0.w, q1.x, q1.y, q1.z, q1.w};
        #pragma unroll
        for (int j = 0; j < 8; j++) {
            float hf;
            phi[n][j] = f2bf_hi(qa[j], &hf);
            plo[n][j] = f2bf(qa[j] - hf);
        }
    }

    float lacc = 0.f, dacc = 0.f, kacc = 0.f;

    #pragma unroll 1
    for (int p0 = (blk * 4 + wave) * 64; p0 < Nb; p0 += BPB * 4 * 64) {
        point_group(p0 + lid,      eb, lb, phi, plo, nabs, sub, lacc, dacc, kacc);
        point_group(p0 + 16 + lid, eb, lb, phi, plo, nabs, sub, lacc, dacc, kacc);
        point_group(p0 + 32 + lid, eb, lb, phi, plo, nabs, sub, lacc, dacc, kacc);
        point_group(p0 + 48 + lid, eb, lb, phi, plo, nabs, sub, lacc, dacc, kacc);
    }

    // v = sum(log2 sums) - sum(label logits); k = kept count
    float v = lacc - dacc;
    #pragma unroll
    for (int m = 32; m >= 1; m >>= 1) {
        v += __shfl_xor(v, m);
        kacc += __shfl_xor(kacc, m);
    }
    if (lane == 0) {
        s_red[wave] = v;
        s_red[4 + wave] = kacc;
    }
    __syncthreads();
    if (t == 0) {
        float a = s_red[0] + s_red[1] + s_red[2] + s_red[3];
        float k = s_red[4] + s_red[5] + s_red[6] + s_red[7];
        unsafeAtomicAdd(lossout + b, LN2 * a);      // WS_LOSS (ln-space)
        unsafeAtomicAdd(lossout + BNUM + b, k);     // WS_KEEP
    }
}

__global__ void k_final(const float* __restrict__ ws, float* __restrict__ out) {
    if (threadIdx.x == 0 && blockIdx.x == 0) {
        float s = 0.f;
        for (int b = 0; b < BNUM; b++) {
            float l = ws[WS_LOSS + b];
            float k = ws[WS_KEEP + b];
            s += l / fmaxf(k, 1.0f);
        }
        out[0] = SEG_W * (s / BNUM);
    }
}

extern "C" void kernel_launch(void* const* d_in, const int* in_sizes, int n_in,
                              void* d_out, int out_size, void* d_ws, size_t ws_size,
                              hipStream_t stream) {
    const float* emb = (const float*)d_in[0];
    const int* lab = (const int*)d_in[1];
    float* ws = (float*)d_ws;
    float* out = (float*)d_out;
    const int total_pts = in_sizes[1];
    const int Nb = total_pts / BNUM;

    hipMemsetAsync(d_ws, 0, WS_TOTAL * sizeof(float), stream);
    constexpr int BPB_ACC = 192;   // 768 blocks -> 3 blocks/CU exact (LDS ~44KB/block)
    constexpr int BPB_LOSS = 256;  // 1024 blocks, 4 iters/wave of 4x16 points
    k_accum<BPB_ACC><<<dim3(BNUM * BPB_ACC), dim3(256), 0, stream>>>(emb, lab, ws, Nb);
    k_proto<<<dim3(BNUM), dim3(256), 0, stream>>>(ws);
    k_loss<BPB_LOSS><<<dim3(BNUM * BPB_LOSS), dim3(256), 0, stream>>>(
        emb, lab, ws + WS_PROT, ws + WS_NABS, ws + WS_LOSS, Nb);
    k_final<<<1, 64, 0, stream>>>(ws, out);
}